// Round 2
// baseline (4957.468 us; speedup 1.0000x reference)
//
#include <hip/hip_runtime.h>
#include <hip/hip_bf16.h>

#define INFV 1e9f
#define EPSV 1e-5f

typedef unsigned short u16;
typedef unsigned int u32;
typedef unsigned short us4v __attribute__((ext_vector_type(4)));
typedef unsigned short us8v __attribute__((ext_vector_type(8)));

__device__ __forceinline__ float us2f(u16 u) {
    u32 v = ((u32)u) << 16;
    float f;
    __builtin_memcpy(&f, &v, 4);
    return f;
}

__device__ __forceinline__ u16 f2us(float f) {
    u32 v;
    __builtin_memcpy(&v, &f, 4);
    u32 r = v + 0x7fffu + ((v >> 16) & 1u);
    return (u16)(r >> 16);
}

// ---- dtype-dispatched load/store helpers ----
template<bool FP32> __device__ __forceinline__ float ld1(const void* p, size_t i) {
    if constexpr (FP32) return ((const float*)p)[i];
    else return us2f(((const u16*)p)[i]);
}
template<bool FP32> __device__ __forceinline__ void ld2(const void* p, size_t i, float* o) {
    if constexpr (FP32) { float2 v = *(const float2*)((const float*)p + i); o[0] = v.x; o[1] = v.y; }
    else { ushort2 v = *(const ushort2*)((const u16*)p + i); o[0] = us2f(v.x); o[1] = us2f(v.y); }
}
template<bool FP32> __device__ __forceinline__ void ld4(const void* p, size_t i, float* o) {
    if constexpr (FP32) {
        float4 v = *(const float4*)((const float*)p + i);
        o[0] = v.x; o[1] = v.y; o[2] = v.z; o[3] = v.w;
    } else {
        us4v v = *(const us4v*)((const u16*)p + i);
        #pragma unroll
        for (int j = 0; j < 4; j++) o[j] = us2f(v[j]);
    }
}
template<bool FP32> __device__ __forceinline__ void ld8(const void* p, size_t i, float* o) {
    if constexpr (FP32) {
        const float4* q = (const float4*)((const float*)p + i);
        float4 a = q[0], b = q[1];
        o[0] = a.x; o[1] = a.y; o[2] = a.z; o[3] = a.w;
        o[4] = b.x; o[5] = b.y; o[6] = b.z; o[7] = b.w;
    } else {
        us8v v = *(const us8v*)((const u16*)p + i);
        #pragma unroll
        for (int j = 0; j < 8; j++) o[j] = us2f(v[j]);
    }
}
template<bool FP32> __device__ __forceinline__ void st1(void* p, size_t i, float v) {
    if constexpr (FP32) ((float*)p)[i] = v;
    else ((u16*)p)[i] = f2us(v);
}

__device__ __forceinline__ float wred_sum(float x) {
    #pragma unroll
    for (int o = 32; o; o >>= 1) x += __shfl_xor(x, o);
    return x;
}

__device__ __forceinline__ float wred_max(float x) {
    #pragma unroll
    for (int o = 32; o; o >>= 1) x = fmaxf(x, __shfl_xor(x, o));
    return x;
}

// K1 body: per (q,k) pair: LN(z) over 128 ch, 8 logits -> wbuf[q][k][h]
template<bool FP32>
__device__ __forceinline__ void body_logits(
    const void* __restrict__ z, const void* __restrict__ mask,
    const void* __restrict__ gz, const void* __restrict__ bz,
    const void* __restrict__ wz, const void* __restrict__ bzb,
    float* __restrict__ wbuf)
{
    const int pair = blockIdx.x * 4 + (threadIdx.x >> 6);
    const int lane = threadIdx.x & 63;
    float x[2];
    ld2<FP32>(z, (size_t)pair * 128 + 2 * lane, x);
    const float mean = wred_sum(x[0] + x[1]) * (1.0f / 128.0f);
    const float d0 = x[0] - mean, d1 = x[1] - mean;
    const float var = wred_sum(d0 * d0 + d1 * d1) * (1.0f / 128.0f);
    const float rs = rsqrtf(var + EPSV);
    const int c0 = 2 * lane;
    const float zn0 = d0 * rs * ld1<FP32>(gz, c0) + ld1<FP32>(bz, c0);
    const float zn1 = d1 * rs * ld1<FP32>(gz, c0 + 1) + ld1<FP32>(bz, c0 + 1);
    float wa[8], wb[8];
    ld8<FP32>(wz, (size_t)c0 * 8, wa);
    ld8<FP32>(wz, (size_t)(c0 + 1) * 8, wb);
    float myv = 0.0f;
    #pragma unroll
    for (int h = 0; h < 8; h++) {
        float p = zn0 * wa[h] + zn1 * wb[h];
        p = wred_sum(p);
        if (lane == h) myv = p;
    }
    if (lane < 8) {
        const float mb = INFV * (ld1<FP32>(mask, pair) - 1.0f);
        wbuf[(size_t)pair * 8 + lane] = myv + ld1<FP32>(bzb, lane) + mb;
    }
}

__global__ __launch_bounds__(256) void k_logits(
    const void* __restrict__ z, const void* __restrict__ mask,
    const void* __restrict__ gz, const void* __restrict__ bz,
    const void* __restrict__ wz, const void* __restrict__ bzb,
    float* __restrict__ wbuf)
{
    if (((const u16*)gz)[0] == 0) body_logits<true>(z, mask, gz, bz, wz, bzb, wbuf);
    else                          body_logits<false>(z, mask, gz, bz, wz, bzb, wbuf);
}

// K2: softmax over k (384) per (q,h) row, in place in ws (always fp32).
__global__ __launch_bounds__(256) void k_softmax(float* __restrict__ wbuf)
{
    const int r = blockIdx.x * 4 + (threadIdx.x >> 6);
    const int lane = threadIdx.x & 63;
    const int q = r >> 3, h = r & 7;
    float* base = wbuf + (size_t)q * 3072 + h;
    float v[6];
    float mx = -1e30f;
    #pragma unroll
    for (int j = 0; j < 6; j++) {
        v[j] = base[(lane + j * 64) * 8];
        mx = fmaxf(mx, v[j]);
    }
    mx = wred_max(mx);
    float s = 0.0f;
    #pragma unroll
    for (int j = 0; j < 6; j++) {
        v[j] = __expf(v[j] - mx);
        s += v[j];
    }
    s = wred_sum(s);
    const float inv = 1.0f / s;
    #pragma unroll
    for (int j = 0; j < 6; j++) base[(lane + j * 64) * 8] = v[j] * inv;
}

// K4 body: fused LN(m) -> v, weighted average over k, gate, out-projection.
template<bool FP32>
__device__ __forceinline__ void body_fused(
    const void* __restrict__ m,
    const void* __restrict__ gm, const void* __restrict__ bm,
    const void* __restrict__ wv, const void* __restrict__ bv,
    const void* __restrict__ wg, const void* __restrict__ bg,
    const void* __restrict__ wo, const void* __restrict__ bo,
    const float* __restrict__ wbuf, void* __restrict__ out)
{
    __shared__ float mnq[64][64];   // 16 KB
    __shared__ float mnk[32][64];   // 8 KB
    __shared__ u16   vt[32][256];   // 16 KB
    __shared__ u16   og[64][256];   // 32 KB

    const int tid  = threadIdx.x;
    const int lane = tid & 63;
    const int wid  = tid >> 6;
    const int s    = blockIdx.y;
    const int q0   = blockIdx.x * 64;

    const float gmv = ld1<FP32>(gm, lane), bmv = ld1<FP32>(bm, lane);

    // stage LN(m) for q rows
    for (int row = wid; row < 64; row += 4) {
        const float x = ld1<FP32>(m, ((size_t)s * 384 + (q0 + row)) * 64 + lane);
        const float mean = wred_sum(x) * (1.0f / 64.0f);
        const float d = x - mean;
        const float var = wred_sum(d * d) * (1.0f / 64.0f);
        mnq[row][lane] = d * rsqrtf(var + EPSV) * gmv + bmv;
    }

    const int tq  = tid >> 5;
    const int th  = tid & 31;
    const int h   = th >> 2;
    const int hcb = h * 32 + (th & 3) * 8;

    const int hc4 = (tid & 63) * 4;
    const int kkg = tid >> 6;

    float acc[8][8];
    #pragma unroll
    for (int i = 0; i < 8; i++)
        #pragma unroll
        for (int j = 0; j < 8; j++) acc[i][j] = 0.0f;

    for (int kt = 0; kt < 12; kt++) {
        const int k0 = kt * 32;
        // stage LN(m) for k rows
        for (int row = wid; row < 32; row += 4) {
            const float x = ld1<FP32>(m, ((size_t)s * 384 + (k0 + row)) * 64 + lane);
            const float mean = wred_sum(x) * (1.0f / 64.0f);
            const float d = x - mean;
            const float var = wred_sum(d * d) * (1.0f / 64.0f);
            mnk[row][lane] = d * rsqrtf(var + EPSV) * gmv + bmv;
        }
        __syncthreads();

        // v tile: v[kk][hc] = mnk[kk][:] . wv[:,hc] + bv
        float va[8][4];
        #pragma unroll
        for (int r = 0; r < 8; r++) {
            float b4[4];
            ld4<FP32>(bv, hc4, b4);
            #pragma unroll
            for (int cc = 0; cc < 4; cc++) va[r][cc] = b4[cc];
        }
        for (int c = 0; c < 64; c++) {
            float w4[4];
            ld4<FP32>(wv, (size_t)c * 256 + hc4, w4);
            #pragma unroll
            for (int r = 0; r < 8; r++) {
                const float mv = mnk[kkg * 8 + r][c];
                va[r][0] = fmaf(mv, w4[0], va[r][0]);
                va[r][1] = fmaf(mv, w4[1], va[r][1]);
                va[r][2] = fmaf(mv, w4[2], va[r][2]);
                va[r][3] = fmaf(mv, w4[3], va[r][3]);
            }
        }
        #pragma unroll
        for (int r = 0; r < 8; r++) {
            us4v st;
            st[0] = f2us(va[r][0]); st[1] = f2us(va[r][1]);
            st[2] = f2us(va[r][2]); st[3] = f2us(va[r][3]);
            *(us4v*)&vt[kkg * 8 + r][hc4] = st;
        }
        __syncthreads();

        // weighted accumulation
        const float* wb = wbuf + (size_t)(q0 + tq) * 3072 + (size_t)k0 * 8 + h;
        for (int kk = 0; kk < 32; kk++) {
            const us8v v8u = *(const us8v*)&vt[kk][hcb];
            float v8[8];
            #pragma unroll
            for (int j = 0; j < 8; j++) v8[j] = us2f(v8u[j]);
            #pragma unroll
            for (int i = 0; i < 8; i++) {
                const float wval = wb[(size_t)i * 24576 + kk * 8];
                #pragma unroll
                for (int cc = 0; cc < 8; cc++)
                    acc[i][cc] = fmaf(wval, v8[cc], acc[i][cc]);
            }
        }
        __syncthreads();
    }

    // gate + write o*g (bf16) to LDS
    #pragma unroll
    for (int i = 0; i < 8; i++) {
        const int q = tq + 8 * i;
        float ga[8];
        ld8<FP32>(bg, hcb, ga);
        for (int c = 0; c < 64; c++) {
            const float mq = mnq[q][c];
            float g8[8];
            ld8<FP32>(wg, (size_t)c * 256 + hcb, g8);
            #pragma unroll
            for (int cc = 0; cc < 8; cc++)
                ga[cc] = fmaf(mq, g8[cc], ga[cc]);
        }
        us8v st;
        #pragma unroll
        for (int cc = 0; cc < 8; cc++) {
            const float sg = 1.0f / (1.0f + __expf(-ga[cc]));
            st[cc] = f2us(acc[i][cc] * sg);
        }
        *(us8v*)&og[q][hcb] = st;
    }
    __syncthreads();

    // out projection
    const int e = tid & 63;
    const int qi = tid >> 6;
    #pragma unroll 4
    for (int i = 0; i < 16; i++) {
        const int q = qi + 4 * i;
        float oa = ld1<FP32>(bo, e);
        for (int hcc = 0; hcc < 256; hcc += 8) {
            const us8v o8 = *(const us8v*)&og[q][hcc];
            #pragma unroll
            for (int j = 0; j < 8; j++)
                oa = fmaf(us2f(o8[j]), ld1<FP32>(wo, (size_t)(hcc + j) * 64 + e), oa);
        }
        st1<FP32>(out, ((size_t)s * 384 + (q0 + q)) * 64 + e, oa);
    }
}

__global__ __launch_bounds__(256, 2) void k_fused(
    const void* __restrict__ m,
    const void* __restrict__ gm, const void* __restrict__ bm,
    const void* __restrict__ wv, const void* __restrict__ bv,
    const void* __restrict__ wg, const void* __restrict__ bg,
    const void* __restrict__ wo, const void* __restrict__ bo,
    const float* __restrict__ wbuf, void* __restrict__ out)
{
    if (((const u16*)gm)[0] == 0)
        body_fused<true >(m, gm, bm, wv, bv, wg, bg, wo, bo, wbuf, out);
    else
        body_fused<false>(m, gm, bm, wv, bv, wg, bg, wo, bo, wbuf, out);
}

extern "C" void kernel_launch(void* const* d_in, const int* in_sizes, int n_in,
                              void* d_out, int out_size, void* d_ws, size_t ws_size,
                              hipStream_t stream) {
    const void* m    = d_in[0];
    const void* z    = d_in[1];
    const void* mask = d_in[2];
    const void* gm   = d_in[3];
    const void* bm   = d_in[4];
    const void* gz   = d_in[5];
    const void* bz   = d_in[6];
    const void* wz   = d_in[7];
    const void* bzb  = d_in[8];
    const void* wv   = d_in[9];
    const void* bv   = d_in[10];
    const void* wg   = d_in[11];
    const void* bg   = d_in[12];
    const void* wo   = d_in[13];
    const void* bo   = d_in[14];
    float* wbuf = (float*)d_ws;   // 384*384*8 fp32 = 4.7 MB, layout [q][k][h]

    k_logits <<<36864, 256, 0, stream>>>(z, mask, gz, bz, wz, bzb, wbuf);
    k_softmax<<<768,   256, 0, stream>>>(wbuf);
    k_fused  <<<dim3(6, 512), 256, 0, stream>>>(m, gm, bm, wv, bv, wg, bg, wo, bo, wbuf, d_out);
}

// Round 3
// 960.330 us; speedup vs baseline: 5.1623x; 5.1623x over previous
//
#include <hip/hip_runtime.h>
#include <hip/hip_bf16.h>

#define INFV 1e9f
#define EPSV 1e-5f

typedef unsigned short u16;
typedef unsigned int u32;
typedef __attribute__((ext_vector_type(8))) short short8;   // 8 bf16 = 4 VGPR (MFMA A/B frag)
typedef __attribute__((ext_vector_type(4))) float float4v;  // MFMA C/D frag

__device__ __forceinline__ float us2f(u16 u) {
    u32 v = ((u32)u) << 16;
    float f;
    __builtin_memcpy(&f, &v, 4);
    return f;
}

__device__ __forceinline__ u16 f2us(float f) {
    u32 v;
    __builtin_memcpy(&v, &f, 4);
    u32 r = v + 0x7fffu + ((v >> 16) & 1u);
    return (u16)(r >> 16);
}

__device__ __forceinline__ float wred_sum(float x) {
    #pragma unroll
    for (int o = 32; o; o >>= 1) x += __shfl_xor(x, o);
    return x;
}

__device__ __forceinline__ float wred_max(float x) {
    #pragma unroll
    for (int o = 32; o; o >>= 1) x = fmaxf(x, __shfl_xor(x, o));
    return x;
}

// ---------------- prep: convert projection weights to bf16, transposed ----------------
// wv (fp32 [64][256])  -> wv_t (bf16 [256][64])
// wg (fp32 [64][256])  -> wg_t (bf16 [256][64])
// wo (fp32 [256][64])  -> wo_t (bf16 [64][256])
__global__ __launch_bounds__(256) void k_prep(
    const float* __restrict__ wv, const float* __restrict__ wg, const float* __restrict__ wo,
    u16* __restrict__ wv_t, u16* __restrict__ wg_t, u16* __restrict__ wo_t)
{
    const int t = threadIdx.x;       // 256 threads, one block
    // wv_t / wg_t: thread t = output row n, loop k
    for (int k = 0; k < 64; k++) {
        wv_t[t * 64 + k] = f2us(wv[(size_t)k * 256 + t]);
        wg_t[t * 64 + k] = f2us(wg[(size_t)k * 256 + t]);
    }
    // wo_t: 16384 elems
    for (int idx = t; idx < 16384; idx += 256) {
        const int n = idx & 63, k = idx >> 6;
        wo_t[(size_t)n * 256 + k] = f2us(wo[(size_t)k * 64 + n]);
    }
}

// ---------------- K1: logits, layout [h][q][k] fp32 ----------------
__global__ __launch_bounds__(256) void k_logits(
    const float* __restrict__ z, const float* __restrict__ mask,
    const float* __restrict__ gz, const float* __restrict__ bz,
    const float* __restrict__ wz, const float* __restrict__ bzb,
    float* __restrict__ wbuf)
{
    const int pair = blockIdx.x * 4 + (threadIdx.x >> 6); // q*384+k, 0..147455
    const int lane = threadIdx.x & 63;
    const float2 xz = *(const float2*)(z + (size_t)pair * 128 + 2 * lane);
    const float mean = wred_sum(xz.x + xz.y) * (1.0f / 128.0f);
    const float d0 = xz.x - mean, d1 = xz.y - mean;
    const float var = wred_sum(d0 * d0 + d1 * d1) * (1.0f / 128.0f);
    const float rs = rsqrtf(var + EPSV);
    const int c0 = 2 * lane;
    const float zn0 = d0 * rs * gz[c0] + bz[c0];
    const float zn1 = d1 * rs * gz[c0 + 1] + bz[c0 + 1];
    const float4 wa0 = *(const float4*)(wz + (size_t)c0 * 8);
    const float4 wa1 = *(const float4*)(wz + (size_t)c0 * 8 + 4);
    const float4 wb0 = *(const float4*)(wz + (size_t)(c0 + 1) * 8);
    const float4 wb1 = *(const float4*)(wz + (size_t)(c0 + 1) * 8 + 4);
    float wa[8] = {wa0.x, wa0.y, wa0.z, wa0.w, wa1.x, wa1.y, wa1.z, wa1.w};
    float wb[8] = {wb0.x, wb0.y, wb0.z, wb0.w, wb1.x, wb1.y, wb1.z, wb1.w};
    float myv = 0.0f;
    #pragma unroll
    for (int h = 0; h < 8; h++) {
        float p = zn0 * wa[h] + zn1 * wb[h];
        p = wred_sum(p);
        if (lane == h) myv = p;
    }
    if (lane < 8) {
        const float mb = INFV * (mask[pair] - 1.0f);
        wbuf[(size_t)lane * 147456 + pair] = myv + bzb[lane] + mb;
    }
}

// ---------------- K2: softmax over k per (h,q) row; fp32 in -> bf16 out ----------------
__global__ __launch_bounds__(256) void k_softmax(
    const float* __restrict__ wbuf, u16* __restrict__ wb16)
{
    const int r = blockIdx.x * 4 + (threadIdx.x >> 6);  // (h,q) row, 0..3071
    const int lane = threadIdx.x & 63;
    const float* base = wbuf + (size_t)r * 384;
    float v[6];
    float mx = -1e30f;
    #pragma unroll
    for (int j = 0; j < 6; j++) {
        v[j] = base[lane + j * 64];
        mx = fmaxf(mx, v[j]);
    }
    mx = wred_max(mx);
    float s = 0.0f;
    #pragma unroll
    for (int j = 0; j < 6; j++) {
        v[j] = __expf(v[j] - mx);
        s += v[j];
    }
    s = wred_sum(s);
    const float inv = 1.0f / s;
    u16* ob = wb16 + (size_t)r * 384;
    #pragma unroll
    for (int j = 0; j < 6; j++) ob[lane + j * 64] = f2us(v[j] * inv);
}

// ---------------- K4: fused MFMA kernel ----------------
// block = (s, 64-q tile). 4 waves.
// MFMA 16x16x32 bf16 frag layouts:
//   A: lane holds A[m=lane&15][k=(lane>>4)*8 + j], j=0..7 contiguous
//   B: lane holds B[k=(lane>>4)*8 + j][n=lane&15]
//   D: lane reg r holds D[row=(lane>>4)*4 + r][col=lane&15]
__global__ __launch_bounds__(256, 2) void k_fused2(
    const float* __restrict__ m,
    const float* __restrict__ gm, const float* __restrict__ bm,
    const float* __restrict__ bv, const float* __restrict__ bg, const float* __restrict__ bo,
    const u16* __restrict__ wv_t, const u16* __restrict__ wg_t, const u16* __restrict__ wo_t,
    const u16* __restrict__ wb16, float* __restrict__ out)
{
    __shared__ __align__(16) u16 mq[64][72];    // LN'd q rows (bf16), 9216 B
    __shared__ __align__(16) u16 mk[32][72];    // LN'd k rows for chunk, 4608 B
    __shared__ __align__(16) u16 vtt[256][40];  // v-chunk transposed [hc][k], 20480 B
    __shared__ __align__(16) u16 og[64][264];   // o*g [q][hc], 33792 B          (sum 68 KB)

    const int tid  = threadIdx.x;
    const int lane = tid & 63;
    const int wid  = tid >> 6;
    const int lrow = lane & 15;
    const int lkg  = lane >> 4;
    const int s    = blockIdx.y;
    const int q0   = blockIdx.x * 64;

    const float gmv = gm[lane], bmv = bm[lane];

    // ---- LN q rows -> mq (bf16) ----
    for (int row = wid; row < 64; row += 4) {
        const float x = m[((size_t)s * 384 + q0 + row) * 64 + lane];
        const float mean = wred_sum(x) * (1.0f / 64.0f);
        const float d = x - mean;
        const float var = wred_sum(d * d) * (1.0f / 64.0f);
        mq[row][lane] = f2us(d * rsqrtf(var + EPSV) * gmv + bmv);
    }

    // v-GEMM wave assignment: mtile = wid&1, ntiles (wid>>1)*8 .. +7
    const int vmt  = wid & 1;
    const int vnt0 = (wid >> 1) * 8;
    float bvv[8];
    #pragma unroll
    for (int i = 0; i < 8; i++) bvv[i] = bv[(vnt0 + i) * 16 + lrow];

    float4v oacc[16];
    #pragma unroll
    for (int nt = 0; nt < 16; nt++) oacc[nt] = (float4v){0.f, 0.f, 0.f, 0.f};

    // per-wave base into softmax weights: row q = q0 + wid*16 + lrow
    const u16* wrow = wb16 + (size_t)(q0 + wid * 16 + lrow) * 384;

    for (int kt = 0; kt < 12; kt++) {
        const int k0 = kt * 32;
        // ---- LN k rows -> mk ----
        for (int row = wid; row < 32; row += 4) {
            const float x = m[((size_t)s * 384 + k0 + row) * 64 + lane];
            const float mean = wred_sum(x) * (1.0f / 64.0f);
            const float d = x - mean;
            const float var = wred_sum(d * d) * (1.0f / 64.0f);
            mk[row][lane] = f2us(d * rsqrtf(var + EPSV) * gmv + bmv);
        }
        __syncthreads();

        // ---- v-GEMM: v[32k][256hc] = mk @ wv_t^T, write transposed to vtt[hc][k] ----
        float4v vacc[8];
        #pragma unroll
        for (int nt = 0; nt < 8; nt++) vacc[nt] = (float4v){bvv[nt], bvv[nt], bvv[nt], bvv[nt]};
        #pragma unroll
        for (int ks = 0; ks < 2; ks++) {
            const short8 a = *(const short8*)&mk[vmt * 16 + lrow][ks * 32 + lkg * 8];
            #pragma unroll
            for (int nt = 0; nt < 8; nt++) {
                const short8 b = *(const short8*)(wv_t + (size_t)((vnt0 + nt) * 16 + lrow) * 64 + ks * 32 + lkg * 8);
                vacc[nt] = __builtin_amdgcn_mfma_f32_16x16x32_bf16(a, b, vacc[nt], 0, 0, 0);
            }
        }
        #pragma unroll
        for (int nt = 0; nt < 8; nt++)
            #pragma unroll
            for (int r = 0; r < 4; r++)
                vtt[(vnt0 + nt) * 16 + lrow][vmt * 16 + lkg * 4 + r] = f2us(vacc[nt][r]);
        __syncthreads();

        // ---- o-GEMM accumulate: oacc[q-subtile wid][all 16 hc tiles] ----
        short8 ah[8];
        #pragma unroll
        for (int h = 0; h < 8; h++)
            ah[h] = *(const short8*)(wrow + (size_t)h * 147456 + k0 + lkg * 8);
        #pragma unroll
        for (int nt = 0; nt < 16; nt++) {
            const short8 b = *(const short8*)&vtt[nt * 16 + lrow][lkg * 8];
            oacc[nt] = __builtin_amdgcn_mfma_f32_16x16x32_bf16(ah[nt >> 1], b, oacc[nt], 0, 0, 0);
        }
        __syncthreads();
    }

    // ---- g-GEMM (same tiling as o) + sigmoid + o*g -> og (bf16) ----
    {
        float4v gacc[16];
        #pragma unroll
        for (int nt = 0; nt < 16; nt++) {
            const float bgv = bg[nt * 16 + lrow];
            gacc[nt] = (float4v){bgv, bgv, bgv, bgv};
        }
        #pragma unroll
        for (int ks = 0; ks < 2; ks++) {
            const short8 a = *(const short8*)&mq[wid * 16 + lrow][ks * 32 + lkg * 8];
            #pragma unroll
            for (int nt = 0; nt < 16; nt++) {
                const short8 b = *(const short8*)(wg_t + (size_t)(nt * 16 + lrow) * 64 + ks * 32 + lkg * 8);
                gacc[nt] = __builtin_amdgcn_mfma_f32_16x16x32_bf16(a, b, gacc[nt], 0, 0, 0);
            }
        }
        #pragma unroll
        for (int nt = 0; nt < 16; nt++)
            #pragma unroll
            for (int r = 0; r < 4; r++) {
                const float sg = 1.0f / (1.0f + __expf(-gacc[nt][r]));
                og[wid * 16 + lkg * 4 + r][nt * 16 + lrow] = f2us(oacc[nt][r] * sg);
            }
    }
    __syncthreads();

    // ---- out-GEMM: out[64q][64e] = og @ wo_t^T ----
    {
        float4v fac[4];
        #pragma unroll
        for (int nt = 0; nt < 4; nt++) {
            const float bov = bo[nt * 16 + lrow];
            fac[nt] = (float4v){bov, bov, bov, bov};
        }
        #pragma unroll
        for (int ks = 0; ks < 8; ks++) {
            const short8 a = *(const short8*)&og[wid * 16 + lrow][ks * 32 + lkg * 8];
            #pragma unroll
            for (int nt = 0; nt < 4; nt++) {
                const short8 b = *(const short8*)(wo_t + (size_t)(nt * 16 + lrow) * 256 + ks * 32 + lkg * 8);
                fac[nt] = __builtin_amdgcn_mfma_f32_16x16x32_bf16(a, b, fac[nt], 0, 0, 0);
            }
        }
        #pragma unroll
        for (int nt = 0; nt < 4; nt++)
            #pragma unroll
            for (int r = 0; r < 4; r++)
                out[((size_t)s * 384 + q0 + wid * 16 + lkg * 4 + r) * 64 + nt * 16 + lrow] = fac[nt][r];
    }
}

extern "C" void kernel_launch(void* const* d_in, const int* in_sizes, int n_in,
                              void* d_out, int out_size, void* d_ws, size_t ws_size,
                              hipStream_t stream) {
    const float* m    = (const float*)d_in[0];
    const float* z    = (const float*)d_in[1];
    const float* mask = (const float*)d_in[2];
    const float* gm   = (const float*)d_in[3];
    const float* bm   = (const float*)d_in[4];
    const float* gz   = (const float*)d_in[5];
    const float* bz   = (const float*)d_in[6];
    const float* wz   = (const float*)d_in[7];
    const float* bzb  = (const float*)d_in[8];
    const float* wv   = (const float*)d_in[9];
    const float* bv   = (const float*)d_in[10];
    const float* wg   = (const float*)d_in[11];
    const float* bg   = (const float*)d_in[12];
    const float* wo   = (const float*)d_in[13];
    const float* bo   = (const float*)d_in[14];
    float* out = (float*)d_out;

    // ws layout
    char* ws = (char*)d_ws;
    float* wbuf = (float*)ws;                               // [8][384][384] fp32 logits, 4,718,592 B
    u16*  wb16  = (u16*)(ws + 4718592);                     // [8][384][384] bf16 softmax w, 2,359,296 B
    u16*  wv_t  = (u16*)(ws + 4718592 + 2359296);           // [256][64] bf16
    u16*  wg_t  = (u16*)(ws + 4718592 + 2359296 + 32768);   // [256][64] bf16
    u16*  wo_t  = (u16*)(ws + 4718592 + 2359296 + 65536);   // [64][256] bf16

    k_prep   <<<1,     256, 0, stream>>>(wv, wg, wo, wv_t, wg_t, wo_t);
    k_logits <<<36864, 256, 0, stream>>>(z, mask, gz, bz, wz, bzb, wbuf);
    k_softmax<<<768,   256, 0, stream>>>(wbuf, wb16);
    k_fused2 <<<dim3(6, 512), 256, 0, stream>>>(m, gm, bm, bv, bg, bo, wv_t, wg_t, wo_t, wb16, out);
}

// Round 4
// 558.062 us; speedup vs baseline: 8.8834x; 1.7208x over previous
//
#include <hip/hip_runtime.h>
#include <hip/hip_bf16.h>

#define INFV 1e9f
#define EPSV 1e-5f

typedef unsigned short u16;
typedef unsigned int u32;
typedef __attribute__((ext_vector_type(8))) short short8;   // 8 bf16 (MFMA A/B frag)
typedef __attribute__((ext_vector_type(4))) float float4v;  // MFMA C/D frag

__device__ __forceinline__ u16 f2us(float f) {
    u32 v;
    __builtin_memcpy(&v, &f, 4);
    u32 r = v + 0x7fffu + ((v >> 16) & 1u);
    return (u16)(r >> 16);
}

__device__ __forceinline__ float wred_sum(float x) {
    #pragma unroll
    for (int o = 32; o; o >>= 1) x += __shfl_xor(x, o);
    return x;
}
__device__ __forceinline__ float wred_max(float x) {
    #pragma unroll
    for (int o = 32; o; o >>= 1) x = fmaxf(x, __shfl_xor(x, o));
    return x;
}

// ---------------- prep: bf16-transposed weights (parallel) ----------------
// wv fp32[64][256] -> wv_t bf16[256][64]; wg likewise; wo fp32[256][64] -> wo_t bf16[64][256];
// wz fp32[128][8] -> wzT bf16[16][128] (rows 8..15 zero)
__global__ __launch_bounds__(256) void k_prep2(
    const float* __restrict__ wv, const float* __restrict__ wg,
    const float* __restrict__ wo, const float* __restrict__ wz,
    u16* __restrict__ wv_t, u16* __restrict__ wg_t,
    u16* __restrict__ wo_t, u16* __restrict__ wzT)
{
    const int i = blockIdx.x * 256 + threadIdx.x;   // 0..51199
    if (i < 16384) {
        const int n = i >> 6, k = i & 63;
        wv_t[i] = f2us(wv[(size_t)k * 256 + n]);
    } else if (i < 32768) {
        const int j = i - 16384, n = j >> 6, k = j & 63;
        wg_t[j] = f2us(wg[(size_t)k * 256 + n]);
    } else if (i < 49152) {
        const int j = i - 32768, n = j >> 8, k = j & 255;
        wo_t[j] = f2us(wo[(size_t)k * 64 + n]);
    } else if (i < 51200) {
        const int j = i - 49152, n = j >> 7, k = j & 127;
        wzT[j] = (n < 8) ? f2us(wz[(size_t)k * 8 + n]) : (u16)0;
    }
}

// ---------------- LN(m) -> mn bf16 [512*384][64] ----------------
// wave handles 4 rows (16 lanes per row, 4 ch each)
__global__ __launch_bounds__(256) void k_ln(
    const float* __restrict__ m, const float* __restrict__ gm, const float* __restrict__ bm,
    u16* __restrict__ mn)
{
    const int tid  = threadIdx.x;
    const int wid  = tid >> 6;
    const int lane = tid & 63;
    const int rloc = lane >> 4;
    const int c4   = (lane & 15) * 4;
    const int row  = blockIdx.x * 16 + wid * 4 + rloc;   // 0..196607
    const float4 x = *(const float4*)(m + (size_t)row * 64 + c4);
    float s1 = x.x + x.y + x.z + x.w;
    float s2 = x.x * x.x + x.y * x.y + x.z * x.z + x.w * x.w;
    #pragma unroll
    for (int o = 8; o; o >>= 1) { s1 += __shfl_xor(s1, o); s2 += __shfl_xor(s2, o); }
    const float mean = s1 * (1.0f / 64.0f);
    const float var  = s2 * (1.0f / 64.0f) - mean * mean;
    const float rs   = rsqrtf(var + EPSV);
    const float4 g = *(const float4*)(gm + c4);
    const float4 b = *(const float4*)(bm + c4);
    u16 o0 = f2us((x.x - mean) * rs * g.x + b.x);
    u16 o1 = f2us((x.y - mean) * rs * g.y + b.y);
    u16 o2 = f2us((x.z - mean) * rs * g.z + b.z);
    u16 o3 = f2us((x.w - mean) * rs * g.w + b.w);
    uint2 pk;
    pk.x = (u32)o0 | ((u32)o1 << 16);
    pk.y = (u32)o2 | ((u32)o3 << 16);
    *(uint2*)(mn + (size_t)row * 64 + c4) = pk;
}

// ---------------- logits via MFMA: wave = 16 pairs ----------------
// wbuf layout [h][pair] fp32 ([8][147456])
__global__ __launch_bounds__(256) void k_logits2(
    const float* __restrict__ z, const float* __restrict__ mask,
    const float* __restrict__ gz, const float* __restrict__ bz,
    const u16* __restrict__ wzT, const float* __restrict__ bzb,
    float* __restrict__ wbuf)
{
    const int tid   = threadIdx.x;
    const int wid   = tid >> 6;
    const int lane  = tid & 63;
    const int lrow  = lane & 15;
    const int lkg   = lane >> 4;
    const int pair0 = (blockIdx.x * 4 + wid) * 16;

    // load 32 z elems per lane (A-frag layout), accumulate LN stats
    float x[4][8];
    float s1 = 0.0f, s2 = 0.0f;
    #pragma unroll
    for (int ks = 0; ks < 4; ks++) {
        const float4* zp = (const float4*)(z + (size_t)(pair0 + lrow) * 128 + ks * 32 + lkg * 8);
        const float4 a = zp[0], b = zp[1];
        x[ks][0] = a.x; x[ks][1] = a.y; x[ks][2] = a.z; x[ks][3] = a.w;
        x[ks][4] = b.x; x[ks][5] = b.y; x[ks][6] = b.z; x[ks][7] = b.w;
        #pragma unroll
        for (int j = 0; j < 8; j++) { s1 += x[ks][j]; s2 += x[ks][j] * x[ks][j]; }
    }
    s1 += __shfl_xor(s1, 16); s1 += __shfl_xor(s1, 32);
    s2 += __shfl_xor(s2, 16); s2 += __shfl_xor(s2, 32);
    const float mean = s1 * (1.0f / 128.0f);
    const float var  = s2 * (1.0f / 128.0f) - mean * mean;
    const float rs   = rsqrtf(var + EPSV);

    float4v acc = (float4v){0.f, 0.f, 0.f, 0.f};
    #pragma unroll
    for (int ks = 0; ks < 4; ks++) {
        const int c0 = ks * 32 + lkg * 8;
        const float4 g0 = *(const float4*)(gz + c0);
        const float4 g1 = *(const float4*)(gz + c0 + 4);
        const float4 b0 = *(const float4*)(bz + c0);
        const float4 b1 = *(const float4*)(bz + c0 + 4);
        const float gv[8] = {g0.x, g0.y, g0.z, g0.w, g1.x, g1.y, g1.z, g1.w};
        const float bvv[8] = {b0.x, b0.y, b0.z, b0.w, b1.x, b1.y, b1.z, b1.w};
        short8 afr;
        #pragma unroll
        for (int j = 0; j < 8; j++)
            afr[j] = (short)f2us((x[ks][j] - mean) * rs * gv[j] + bvv[j]);
        const short8 bfr = *(const short8*)(wzT + (size_t)lrow * 128 + c0);
        acc = __builtin_amdgcn_mfma_f32_16x16x32_bf16(afr, bfr, acc, 0, 0, 0);
    }
    // D: reg r -> pair = pair0 + lkg*4 + r, col lrow = h
    if (lrow < 8) {
        const float bzv = bzb[lrow];
        #pragma unroll
        for (int r = 0; r < 4; r++) {
            const int p = pair0 + lkg * 4 + r;
            const float mb = INFV * (mask[p] - 1.0f);
            wbuf[(size_t)lrow * 147456 + p] = acc[r] + bzv + mb;
        }
    }
}

// ---------------- softmax over k per (h,q) row; fp32 -> bf16 ----------------
__global__ __launch_bounds__(256) void k_softmax(
    const float* __restrict__ wbuf, u16* __restrict__ wb16)
{
    const int r = blockIdx.x * 4 + (threadIdx.x >> 6);
    const int lane = threadIdx.x & 63;
    const float* base = wbuf + (size_t)r * 384;
    float v[6];
    float mx = -1e30f;
    #pragma unroll
    for (int j = 0; j < 6; j++) {
        v[j] = base[lane + j * 64];
        mx = fmaxf(mx, v[j]);
    }
    mx = wred_max(mx);
    float s = 0.0f;
    #pragma unroll
    for (int j = 0; j < 6; j++) {
        v[j] = __expf(v[j] - mx);
        s += v[j];
    }
    s = wred_sum(s);
    const float inv = 1.0f / s;
    u16* ob = wb16 + (size_t)r * 384;
    #pragma unroll
    for (int j = 0; j < 6; j++) ob[lane + j * 64] = f2us(v[j] * inv);
}

// ---------------- fused v / weighted-avg / gate / out ----------------
// block = (s, 128-q tile), 4 waves. One barrier per k-chunk.
__global__ __launch_bounds__(256, 2) void k_fused3(
    const u16* __restrict__ mn,
    const float* __restrict__ bv, const float* __restrict__ bg, const float* __restrict__ bo,
    const u16* __restrict__ wv_t, const u16* __restrict__ wg_t, const u16* __restrict__ wo_t,
    const u16* __restrict__ wb16, float* __restrict__ out)
{
    __shared__ __align__(16) char smem[67584];
    u16* vtt = (u16*)smem;   // [2][256][40]  (double-buffered v chunk, [hc][k])
    u16* og  = (u16*)smem;   // [128][264]    (epilogue o*g tile; reuses vtt space)

    const int tid  = threadIdx.x;
    const int wid  = tid >> 6;
    const int lane = tid & 63;
    const int lrow = lane & 15;
    const int lkg  = lane >> 4;
    const int s    = blockIdx.y;
    const int q0   = blockIdx.x * 128;

    // v-GEMM role: mt = wid&1 (16 k-rows), nt range (wid>>1)*8..+8
    const int vmt  = wid & 1;
    const int vnt0 = (wid >> 1) * 8;
    float bvv[8];
    #pragma unroll
    for (int i = 0; i < 8; i++) bvv[i] = bv[(vnt0 + i) * 16 + lrow];

    float4v oacc[32];   // [mt][nt]: q = q0 + wid*32 + mt*16, hc tile nt
    #pragma unroll
    for (int i = 0; i < 32; i++) oacc[i] = (float4v){0.f, 0.f, 0.f, 0.f};

    for (int kt = 0; kt < 12; kt++) {
        const int k0 = kt * 32;
        // ---- v-GEMM (global A from mn, global B from wv_t) ----
        float4v vacc[8];
        #pragma unroll
        for (int nt = 0; nt < 8; nt++) vacc[nt] = (float4v){bvv[nt], bvv[nt], bvv[nt], bvv[nt]};
        const u16* mnk = mn + ((size_t)s * 384 + k0 + vmt * 16 + lrow) * 64;
        #pragma unroll
        for (int ks = 0; ks < 2; ks++) {
            const short8 a = *(const short8*)(mnk + ks * 32 + lkg * 8);
            #pragma unroll
            for (int nt = 0; nt < 8; nt++) {
                const short8 b = *(const short8*)(wv_t + (size_t)((vnt0 + nt) * 16 + lrow) * 64 + ks * 32 + lkg * 8);
                vacc[nt] = __builtin_amdgcn_mfma_f32_16x16x32_bf16(a, b, vacc[nt], 0, 0, 0);
            }
        }
        // write transposed: vtt[buf][hc][k_local], 4 consecutive k per lane -> b64
        u16* vb = vtt + (size_t)(kt & 1) * 256 * 40;
        #pragma unroll
        for (int nt = 0; nt < 8; nt++) {
            uint2 pk;
            pk.x = (u32)f2us(vacc[nt][0]) | ((u32)f2us(vacc[nt][1]) << 16);
            pk.y = (u32)f2us(vacc[nt][2]) | ((u32)f2us(vacc[nt][3]) << 16);
            *(uint2*)&vb[(size_t)((vnt0 + nt) * 16 + lrow) * 40 + vmt * 16 + lkg * 4] = pk;
        }
        __syncthreads();

        // ---- o-GEMM: A from wb16 (global), B from vtt (LDS) ----
        short8 ah[2][8];
        #pragma unroll
        for (int mt = 0; mt < 2; mt++)
            #pragma unroll
            for (int h = 0; h < 8; h++)
                ah[mt][h] = *(const short8*)(wb16 + (size_t)h * 147456
                              + (size_t)(q0 + wid * 32 + mt * 16 + lrow) * 384 + k0 + lkg * 8);
        #pragma unroll
        for (int nt = 0; nt < 16; nt++) {
            const short8 b = *(const short8*)&vb[(size_t)(nt * 16 + lrow) * 40 + lkg * 8];
            oacc[nt]      = __builtin_amdgcn_mfma_f32_16x16x32_bf16(ah[0][nt >> 1], b, oacc[nt], 0, 0, 0);
            oacc[16 + nt] = __builtin_amdgcn_mfma_f32_16x16x32_bf16(ah[1][nt >> 1], b, oacc[16 + nt], 0, 0, 0);
        }
    }
    __syncthreads();   // all vtt reads done before og overwrite

    // ---- g-GEMM + sigmoid + o*g -> og ----
    #pragma unroll
    for (int mt = 0; mt < 2; mt++) {
        float4v gacc[16];
        #pragma unroll
        for (int nt = 0; nt < 16; nt++) {
            const float bgv = bg[nt * 16 + lrow];
            gacc[nt] = (float4v){bgv, bgv, bgv, bgv};
        }
        const u16* mnq = mn + ((size_t)s * 384 + q0 + wid * 32 + mt * 16 + lrow) * 64;
        #pragma unroll
        for (int ks = 0; ks < 2; ks++) {
            const short8 a = *(const short8*)(mnq + ks * 32 + lkg * 8);
            #pragma unroll
            for (int nt = 0; nt < 16; nt++) {
                const short8 b = *(const short8*)(wg_t + (size_t)(nt * 16 + lrow) * 64 + ks * 32 + lkg * 8);
                gacc[nt] = __builtin_amdgcn_mfma_f32_16x16x32_bf16(a, b, gacc[nt], 0, 0, 0);
            }
        }
        #pragma unroll
        for (int nt = 0; nt < 16; nt++)
            #pragma unroll
            for (int r = 0; r < 4; r++) {
                const float sg = 1.0f / (1.0f + __expf(-gacc[nt][r]));
                og[(size_t)(wid * 32 + mt * 16 + lkg * 4 + r) * 264 + nt * 16 + lrow]
                    = f2us(oacc[mt * 16 + nt][r] * sg);
            }
    }
    __syncthreads();

    // ---- out-GEMM: A from og (LDS), B from wo_t (global) ----
    #pragma unroll
    for (int mt = 0; mt < 2; mt++) {
        float4v fac[4];
        #pragma unroll
        for (int nt = 0; nt < 4; nt++) {
            const float bov = bo[nt * 16 + lrow];
            fac[nt] = (float4v){bov, bov, bov, bov};
        }
        #pragma unroll
        for (int ks = 0; ks < 8; ks++) {
            const short8 a = *(const short8*)&og[(size_t)(wid * 32 + mt * 16 + lrow) * 264 + ks * 32 + lkg * 8];
            #pragma unroll
            for (int nt = 0; nt < 4; nt++) {
                const short8 b = *(const short8*)(wo_t + (size_t)(nt * 16 + lrow) * 256 + ks * 32 + lkg * 8);
                fac[nt] = __builtin_amdgcn_mfma_f32_16x16x32_bf16(a, b, fac[nt], 0, 0, 0);
            }
        }
        #pragma unroll
        for (int nt = 0; nt < 4; nt++)
            #pragma unroll
            for (int r = 0; r < 4; r++)
                out[((size_t)s * 384 + q0 + wid * 32 + mt * 16 + lkg * 4 + r) * 64 + nt * 16 + lrow]
                    = fac[nt][r];
    }
}

extern "C" void kernel_launch(void* const* d_in, const int* in_sizes, int n_in,
                              void* d_out, int out_size, void* d_ws, size_t ws_size,
                              hipStream_t stream) {
    const float* m    = (const float*)d_in[0];
    const float* z    = (const float*)d_in[1];
    const float* mask = (const float*)d_in[2];
    const float* gm   = (const float*)d_in[3];
    const float* bm   = (const float*)d_in[4];
    const float* gz   = (const float*)d_in[5];
    const float* bz   = (const float*)d_in[6];
    const float* wz   = (const float*)d_in[7];
    const float* bzb  = (const float*)d_in[8];
    const float* wv   = (const float*)d_in[9];
    const float* bv   = (const float*)d_in[10];
    const float* wg   = (const float*)d_in[11];
    const float* bg   = (const float*)d_in[12];
    const float* wo   = (const float*)d_in[13];
    const float* bo   = (const float*)d_in[14];
    float* out = (float*)d_out;

    // ws layout (total ~32.5 MB)
    char* ws = (char*)d_ws;
    float* wbuf = (float*)ws;                       // [8][147456] fp32 logits   4,718,592 B
    u16*  wb16  = (u16*)(ws + 4718592);             // [8][147456] bf16 weights  2,359,296 B
    u16*  mn    = (u16*)(ws + 7077888);             // [196608][64] bf16 LN(m)  25,165,824 B
    u16*  wv_t  = (u16*)(ws + 32243712);            // [256][64]  bf16          32,768 B
    u16*  wg_t  = (u16*)(ws + 32276480);            // [256][64]  bf16          32,768 B
    u16*  wo_t  = (u16*)(ws + 32309248);            // [64][256]  bf16          32,768 B
    u16*  wzT   = (u16*)(ws + 32342016);            // [16][128]  bf16           4,096 B

    k_prep2  <<<200,   256, 0, stream>>>(wv, wg, wo, wz, wv_t, wg_t, wo_t, wzT);
    k_ln     <<<12288, 256, 0, stream>>>(m, gm, bm, mn);
    k_logits2<<<2304,  256, 0, stream>>>(z, mask, gz, bz, wzT, bzb, wbuf);
    k_softmax<<<768,   256, 0, stream>>>(wbuf, wb16);
    k_fused3 <<<dim3(3, 512), 256, 0, stream>>>(mn, bv, bg, bo, wv_t, wg_t, wo_t, wb16, out);
}

// Round 5
// 461.852 us; speedup vs baseline: 10.7339x; 1.2083x over previous
//
#include <hip/hip_runtime.h>
#include <hip/hip_bf16.h>

#define INFV 1e9f
#define EPSV 1e-5f

typedef unsigned short u16;
typedef unsigned int u32;
typedef __attribute__((ext_vector_type(8))) short short8;   // 8 bf16 (MFMA A/B frag)
typedef __attribute__((ext_vector_type(4))) float float4v;  // MFMA C/D frag

__device__ __forceinline__ u16 f2us(float f) {
    u32 v;
    __builtin_memcpy(&v, &f, 4);
    u32 r = v + 0x7fffu + ((v >> 16) & 1u);
    return (u16)(r >> 16);
}

__device__ __forceinline__ float wred_sum(float x) {
    #pragma unroll
    for (int o = 32; o; o >>= 1) x += __shfl_xor(x, o);
    return x;
}
__device__ __forceinline__ float wred_max(float x) {
    #pragma unroll
    for (int o = 32; o; o >>= 1) x = fmaxf(x, __shfl_xor(x, o));
    return x;
}

// ---------------- LN(m) -> mn bf16, + weight prep (merged grid) ----------------
// blocks [0,12288): LN.  blocks [12288,12488): weight transpose/convert.
__global__ __launch_bounds__(256) void k_prep_ln(
    const float* __restrict__ m, const float* __restrict__ gm, const float* __restrict__ bm,
    u16* __restrict__ mn,
    const float* __restrict__ wv, const float* __restrict__ wg,
    const float* __restrict__ wo, const float* __restrict__ wz,
    u16* __restrict__ wv_t, u16* __restrict__ wg_t,
    u16* __restrict__ wo_t, u16* __restrict__ wzT)
{
    if (blockIdx.x < 12288) {
        const int tid  = threadIdx.x;
        const int wid  = tid >> 6;
        const int lane = tid & 63;
        const int rloc = lane >> 4;
        const int c4   = (lane & 15) * 4;
        const int row  = blockIdx.x * 16 + wid * 4 + rloc;   // 0..196607
        const float4 x = *(const float4*)(m + (size_t)row * 64 + c4);
        float s1 = x.x + x.y + x.z + x.w;
        float s2 = x.x * x.x + x.y * x.y + x.z * x.z + x.w * x.w;
        #pragma unroll
        for (int o = 8; o; o >>= 1) { s1 += __shfl_xor(s1, o); s2 += __shfl_xor(s2, o); }
        const float mean = s1 * (1.0f / 64.0f);
        const float var  = s2 * (1.0f / 64.0f) - mean * mean;
        const float rs   = rsqrtf(var + EPSV);
        const float4 g = *(const float4*)(gm + c4);
        const float4 b = *(const float4*)(bm + c4);
        uint2 pk;
        pk.x = (u32)f2us((x.x - mean) * rs * g.x + b.x) | ((u32)f2us((x.y - mean) * rs * g.y + b.y) << 16);
        pk.y = (u32)f2us((x.z - mean) * rs * g.z + b.z) | ((u32)f2us((x.w - mean) * rs * g.w + b.w) << 16);
        *(uint2*)(mn + (size_t)row * 64 + c4) = pk;
    } else {
        const int i = (blockIdx.x - 12288) * 256 + threadIdx.x;   // 0..51199
        if (i < 16384) {
            const int n = i >> 6, k = i & 63;
            wv_t[i] = f2us(wv[(size_t)k * 256 + n]);
        } else if (i < 32768) {
            const int j = i - 16384, n = j >> 6, k = j & 63;
            wg_t[j] = f2us(wg[(size_t)k * 256 + n]);
        } else if (i < 49152) {
            const int j = i - 32768, n = j >> 8, k = j & 255;
            wo_t[j] = f2us(wo[(size_t)k * 64 + n]);
        } else if (i < 51200) {
            const int j = i - 49152, n = j >> 7, k = j & 127;
            wzT[j] = (n < 8) ? f2us(wz[(size_t)k * 8 + n]) : (u16)0;
        }
    }
}

// ---------------- logits via MFMA: wave = 16 pairs; wbuf [h][pair] fp32 ----------------
__global__ __launch_bounds__(256) void k_logits2(
    const float* __restrict__ z, const float* __restrict__ mask,
    const float* __restrict__ gz, const float* __restrict__ bz,
    const u16* __restrict__ wzT, const float* __restrict__ bzb,
    float* __restrict__ wbuf)
{
    const int tid   = threadIdx.x;
    const int wid   = tid >> 6;
    const int lane  = tid & 63;
    const int lrow  = lane & 15;
    const int lkg   = lane >> 4;
    const int pair0 = (blockIdx.x * 4 + wid) * 16;

    float x[4][8];
    float s1 = 0.0f, s2 = 0.0f;
    #pragma unroll
    for (int ks = 0; ks < 4; ks++) {
        const float4* zp = (const float4*)(z + (size_t)(pair0 + lrow) * 128 + ks * 32 + lkg * 8);
        const float4 a = zp[0], b = zp[1];
        x[ks][0] = a.x; x[ks][1] = a.y; x[ks][2] = a.z; x[ks][3] = a.w;
        x[ks][4] = b.x; x[ks][5] = b.y; x[ks][6] = b.z; x[ks][7] = b.w;
        #pragma unroll
        for (int j = 0; j < 8; j++) { s1 += x[ks][j]; s2 += x[ks][j] * x[ks][j]; }
    }
    s1 += __shfl_xor(s1, 16); s1 += __shfl_xor(s1, 32);
    s2 += __shfl_xor(s2, 16); s2 += __shfl_xor(s2, 32);
    const float mean = s1 * (1.0f / 128.0f);
    const float var  = s2 * (1.0f / 128.0f) - mean * mean;
    const float rs   = rsqrtf(var + EPSV);

    float4v acc = (float4v){0.f, 0.f, 0.f, 0.f};
    #pragma unroll
    for (int ks = 0; ks < 4; ks++) {
        const int c0 = ks * 32 + lkg * 8;
        const float4 g0 = *(const float4*)(gz + c0);
        const float4 g1 = *(const float4*)(gz + c0 + 4);
        const float4 b0 = *(const float4*)(bz + c0);
        const float4 b1 = *(const float4*)(bz + c0 + 4);
        const float gv[8] = {g0.x, g0.y, g0.z, g0.w, g1.x, g1.y, g1.z, g1.w};
        const float bvv[8] = {b0.x, b0.y, b0.z, b0.w, b1.x, b1.y, b1.z, b1.w};
        short8 afr;
        #pragma unroll
        for (int j = 0; j < 8; j++)
            afr[j] = (short)f2us((x[ks][j] - mean) * rs * gv[j] + bvv[j]);
        const short8 bfr = *(const short8*)(wzT + (size_t)lrow * 128 + c0);
        acc = __builtin_amdgcn_mfma_f32_16x16x32_bf16(afr, bfr, acc, 0, 0, 0);
    }
    if (lrow < 8) {
        const float bzv = bzb[lrow];
        #pragma unroll
        for (int r = 0; r < 4; r++) {
            const int p = pair0 + lkg * 4 + r;
            const float mb = INFV * (mask[p] - 1.0f);
            wbuf[(size_t)lrow * 147456 + p] = acc[r] + bzv + mb;
        }
    }
}

// ---------------- softmax over k per (h,q) row; fp32 -> bf16 ----------------
__global__ __launch_bounds__(256) void k_softmax(
    const float* __restrict__ wbuf, u16* __restrict__ wb16)
{
    const int r = blockIdx.x * 4 + (threadIdx.x >> 6);
    const int lane = threadIdx.x & 63;
    const float* base = wbuf + (size_t)r * 384;
    float v[6];
    float mx = -1e30f;
    #pragma unroll
    for (int j = 0; j < 6; j++) {
        v[j] = base[lane + j * 64];
        mx = fmaxf(mx, v[j]);
    }
    mx = wred_max(mx);
    float s = 0.0f;
    #pragma unroll
    for (int j = 0; j < 6; j++) {
        v[j] = __expf(v[j] - mx);
        s += v[j];
    }
    s = wred_sum(s);
    const float inv = 1.0f / s;
    u16* ob = wb16 + (size_t)r * 384;
    #pragma unroll
    for (int j = 0; j < 6; j++) ob[lane + j * 64] = f2us(v[j] * inv);
}

// ---------------- fused v / weighted-avg / gate / out ----------------
// block = (s, 128-q tile), 4 waves. One barrier per k-chunk.
// vtt layout [kgroup8][hc][8k]: o-GEMM b-read = 2 lanes/bank (conflict-free).
__global__ __launch_bounds__(256, 2) void k_fused4(
    const u16* __restrict__ mn,
    const float* __restrict__ bv, const float* __restrict__ bg, const float* __restrict__ bo,
    const u16* __restrict__ wv_t, const u16* __restrict__ wg_t, const u16* __restrict__ wo_t,
    const u16* __restrict__ wb16, float* __restrict__ out)
{
    __shared__ __align__(16) char smem[67584];
    u16* vtt = (u16*)smem;   // [2][4][256][8]  double-buffered v chunk, 32768 B
    u16* og  = (u16*)smem;   // [128][264]      epilogue o*g tile (reuses vtt)

    const int tid  = threadIdx.x;
    const int wid  = tid >> 6;
    const int lane = tid & 63;
    const int lrow = lane & 15;
    const int lkg  = lane >> 4;
    const int s    = blockIdx.y;
    const int q0   = blockIdx.x * 128;

    // v-GEMM role: vmt = wid&1 (which 16 k-rows), nt range (wid>>1)*8..+8
    const int vmt  = wid & 1;
    const int vnt0 = (wid >> 1) * 8;

    // oacc[mt*16+nt]: q-rows q0+wid*32+mt*16.., hc tile nt. Init = bv (softmax sums to 1).
    float4v oacc[32];
    #pragma unroll
    for (int mt = 0; mt < 2; mt++)
        #pragma unroll
        for (int nt = 0; nt < 16; nt++) {
            const float b = bv[nt * 16 + lrow];
            oacc[mt * 16 + nt] = (float4v){b, b, b, b};
        }

    for (int kt = 0; kt < 12; kt++) {
        const int k0 = kt * 32;
        // ---- v-GEMM: A from mn (global), B from wv_t (global) ----
        float4v vacc[8];
        #pragma unroll
        for (int nt = 0; nt < 8; nt++) vacc[nt] = (float4v){0.f, 0.f, 0.f, 0.f};
        const u16* mnk = mn + ((size_t)s * 384 + k0 + vmt * 16 + lrow) * 64;
        #pragma unroll
        for (int ks = 0; ks < 2; ks++) {
            const short8 a = *(const short8*)(mnk + ks * 32 + lkg * 8);
            #pragma unroll
            for (int nt = 0; nt < 8; nt++) {
                const short8 b = *(const short8*)(wv_t + (size_t)((vnt0 + nt) * 16 + lrow) * 64 + ks * 32 + lkg * 8);
                vacc[nt] = __builtin_amdgcn_mfma_f32_16x16x32_bf16(a, b, vacc[nt], 0, 0, 0);
            }
        }
        // write to vtt[buf][kg8][hc][k&7]: lane's 4 k = vmt*16+lkg*4+r
        u16* vb = vtt + (size_t)(kt & 1) * 8192;
        const int kg8 = vmt * 2 + (lkg >> 1);
        const int ko  = (lkg & 1) * 4;
        #pragma unroll
        for (int nt = 0; nt < 8; nt++) {
            uint2 pk;
            pk.x = (u32)f2us(vacc[nt][0]) | ((u32)f2us(vacc[nt][1]) << 16);
            pk.y = (u32)f2us(vacc[nt][2]) | ((u32)f2us(vacc[nt][3]) << 16);
            *(uint2*)&vb[((size_t)kg8 * 256 + (vnt0 + nt) * 16 + lrow) * 8 + ko] = pk;
        }
        __syncthreads();

        // ---- o-GEMM: A from wb16 (global, L2-hot), B from vtt (LDS) ----
        short8 ah[2][8];
        #pragma unroll
        for (int mt = 0; mt < 2; mt++)
            #pragma unroll
            for (int h = 0; h < 8; h++)
                ah[mt][h] = *(const short8*)(wb16 + (size_t)h * 147456
                              + (size_t)(q0 + wid * 32 + mt * 16 + lrow) * 384 + k0 + lkg * 8);
        #pragma unroll
        for (int nt = 0; nt < 16; nt++) {
            const short8 b = *(const short8*)&vb[((size_t)lkg * 256 + nt * 16 + lrow) * 8];
            oacc[nt]      = __builtin_amdgcn_mfma_f32_16x16x32_bf16(ah[0][nt >> 1], b, oacc[nt], 0, 0, 0);
            oacc[16 + nt] = __builtin_amdgcn_mfma_f32_16x16x32_bf16(ah[1][nt >> 1], b, oacc[16 + nt], 0, 0, 0);
        }
    }
    __syncthreads();   // all vtt reads done before og overwrite

    // ---- g-GEMM per-nt (low reg pressure) + sigmoid + o*g -> og ----
    #pragma unroll
    for (int mt = 0; mt < 2; mt++) {
        const u16* mnq = mn + ((size_t)s * 384 + q0 + wid * 32 + mt * 16 + lrow) * 64;
        const short8 a0 = *(const short8*)(mnq + lkg * 8);
        const short8 a1 = *(const short8*)(mnq + 32 + lkg * 8);
        #pragma unroll
        for (int nt = 0; nt < 16; nt++) {
            const float bgv = bg[nt * 16 + lrow];
            float4v gacc = (float4v){bgv, bgv, bgv, bgv};
            const short8 b0 = *(const short8*)(wg_t + (size_t)(nt * 16 + lrow) * 64 + lkg * 8);
            const short8 b1 = *(const short8*)(wg_t + (size_t)(nt * 16 + lrow) * 64 + 32 + lkg * 8);
            gacc = __builtin_amdgcn_mfma_f32_16x16x32_bf16(a0, b0, gacc, 0, 0, 0);
            gacc = __builtin_amdgcn_mfma_f32_16x16x32_bf16(a1, b1, gacc, 0, 0, 0);
            #pragma unroll
            for (int r = 0; r < 4; r++) {
                const float sg = 1.0f / (1.0f + __expf(-gacc[r]));
                og[(size_t)(wid * 32 + mt * 16 + lkg * 4 + r) * 264 + nt * 16 + lrow]
                    = f2us(oacc[mt * 16 + nt][r] * sg);
            }
        }
    }
    __syncthreads();

    // ---- out-GEMM: A from og (LDS, cached per mt), B from wo_t (global) ----
    #pragma unroll
    for (int mt = 0; mt < 2; mt++) {
        short8 af[8];
        #pragma unroll
        for (int ks = 0; ks < 8; ks++)
            af[ks] = *(const short8*)&og[(size_t)(wid * 32 + mt * 16 + lrow) * 264 + ks * 32 + lkg * 8];
        #pragma unroll
        for (int nt = 0; nt < 4; nt++) {
            const float bov = bo[nt * 16 + lrow];
            float4v fac = (float4v){bov, bov, bov, bov};
            #pragma unroll
            for (int ks = 0; ks < 8; ks++) {
                const short8 b = *(const short8*)(wo_t + (size_t)(nt * 16 + lrow) * 256 + ks * 32 + lkg * 8);
                fac = __builtin_amdgcn_mfma_f32_16x16x32_bf16(af[ks], b, fac, 0, 0, 0);
            }
            #pragma unroll
            for (int r = 0; r < 4; r++)
                out[((size_t)s * 384 + q0 + wid * 32 + mt * 16 + lkg * 4 + r) * 64 + nt * 16 + lrow]
                    = fac[r];
        }
    }
}

extern "C" void kernel_launch(void* const* d_in, const int* in_sizes, int n_in,
                              void* d_out, int out_size, void* d_ws, size_t ws_size,
                              hipStream_t stream) {
    const float* m    = (const float*)d_in[0];
    const float* z    = (const float*)d_in[1];
    const float* mask = (const float*)d_in[2];
    const float* gm   = (const float*)d_in[3];
    const float* bm   = (const float*)d_in[4];
    const float* gz   = (const float*)d_in[5];
    const float* bz   = (const float*)d_in[6];
    const float* wz   = (const float*)d_in[7];
    const float* bzb  = (const float*)d_in[8];
    const float* wv   = (const float*)d_in[9];
    const float* bv   = (const float*)d_in[10];
    const float* wg   = (const float*)d_in[11];
    const float* bg   = (const float*)d_in[12];
    const float* wo   = (const float*)d_in[13];
    const float* bo   = (const float*)d_in[14];
    float* out = (float*)d_out;

    // ws layout (total ~32.5 MB)
    char* ws = (char*)d_ws;
    float* wbuf = (float*)ws;                       // [8][147456] fp32 logits   4,718,592 B
    u16*  wb16  = (u16*)(ws + 4718592);             // [8][147456] bf16 weights  2,359,296 B
    u16*  mn    = (u16*)(ws + 7077888);             // [196608][64] bf16 LN(m)  25,165,824 B
    u16*  wv_t  = (u16*)(ws + 32243712);            // [256][64]  bf16
    u16*  wg_t  = (u16*)(ws + 32276480);            // [256][64]  bf16
    u16*  wo_t  = (u16*)(ws + 32309248);            // [64][256]  bf16
    u16*  wzT   = (u16*)(ws + 32342016);            // [16][128]  bf16

    k_prep_ln<<<12488, 256, 0, stream>>>(m, gm, bm, mn, wv, wg, wo, wz, wv_t, wg_t, wo_t, wzT);
    k_logits2<<<2304,  256, 0, stream>>>(z, mask, gz, bz, wzT, bzb, wbuf);
    k_softmax<<<768,   256, 0, stream>>>(wbuf, wb16);
    k_fused4 <<<dim3(3, 512), 256, 0, stream>>>(mn, bv, bg, bo, wv_t, wg_t, wo_t, wb16, out);
}